// Round 15
// baseline (375.532 us; speedup 1.0000x reference)
//
#include <hip/hip_runtime.h>
#include <cstdint>

// TGN memory update — round 15: depth-3 weight-prefetch ring in gru
// (was depth-1 e/o). M=32, 512 thr, 4 waves/SIMD; linked-list aggregation;
// pure-copy global_load_lds staging; lu_out fused into aggregate.

#define MEMD 128
#define ACCD 384
#define MSGD 512

typedef __attribute__((ext_vector_type(8))) short bf16x8;
typedef __attribute__((ext_vector_type(2))) short bf16x2;
typedef __attribute__((ext_vector_type(4))) float f32x4;

static __device__ __forceinline__ short f2bf(float f) {
    uint32_t u = __builtin_bit_cast(uint32_t, f);
    u = (u + 0x7FFFu + ((u >> 16) & 1u)) >> 16;
    return (short)u;
}
static __device__ __forceinline__ float bf2f(short s) {
    return __builtin_bit_cast(float, ((uint32_t)(uint16_t)s) << 16);
}
// async 16B global->LDS; LDS dest = wave-uniform base + lane*16, global per-lane
static __device__ __forceinline__ void load_lds16(const void* g, void* l) {
    __builtin_amdgcn_global_load_lds(
        (const __attribute__((address_space(1))) unsigned int*)g,
        (__attribute__((address_space(3))) unsigned int*)l,
        16, 0, 0);
}

// ---------------- Prep A: memory f32 -> bf16 ----------------
__global__ __launch_bounds__(256) void tgn_prep_mem(
    const float* __restrict__ mem, short* __restrict__ memB, int n8)
{
    const int i = blockIdx.x * 256 + threadIdx.x;
    if (i >= n8) return;
    const float4 a = *reinterpret_cast<const float4*>(mem + (size_t)i * 8);
    const float4 b = *reinterpret_cast<const float4*>(mem + (size_t)i * 8 + 4);
    bf16x8 v;
    v[0] = f2bf(a.x); v[1] = f2bf(a.y); v[2] = f2bf(a.z); v[3] = f2bf(a.w);
    v[4] = f2bf(b.x); v[5] = f2bf(b.y); v[6] = f2bf(b.z); v[7] = f2bf(b.w);
    *reinterpret_cast<bf16x8*>(memB + (size_t)i * 8) = v;
}

// ---------------- Prep B: weights f32 -> bf16 frag-major ----------------
#define GI_SLOTS (24 * 16 * 64)
#define GH_SLOTS (24 * 4 * 64)

__global__ __launch_bounds__(256) void tgn_prep_w(
    const float* __restrict__ W_ih, const float* __restrict__ W_hh,
    bf16x8* __restrict__ Wb)
{
    const int s = blockIdx.x * 256 + threadIdx.x;
    if (s >= GI_SLOTS + GH_SLOTS) return;
    const float* src;
    if (s < GI_SLOTS) {
        const int n = s / (16 * 64), rem = s % (16 * 64);
        const int ks = rem / 64, l = rem % 64;
        const int j = n * 16 + (l & 15), k = ks * 32 + (l >> 4) * 8;
        src = W_ih + (size_t)j * MSGD + k;
    } else {
        const int s2 = s - GI_SLOTS;
        const int n = s2 / (4 * 64), rem = s2 % (4 * 64);
        const int ks = rem / 64, l = rem % 64;
        const int j = n * 16 + (l & 15), k = ks * 32 + (l >> 4) * 8;
        src = W_hh + (size_t)j * MEMD + k;
    }
    bf16x8 v;
    #pragma unroll
    for (int e = 0; e < 8; ++e) v[e] = f2bf(src[e]);
    Wb[s] = v;
}

// ---------------- Phase 1a: build per-node linked lists ----------------
__global__ __launch_bounds__(256) void tgn_fill(
    const int* __restrict__ src, const int* __restrict__ dst, const int* __restrict__ t,
    int* __restrict__ head, int* __restrict__ nxt, int* __restrict__ lu_new,
    int n_events)
{
    const int e = blockIdx.x * 256 + threadIdx.x;
    if (e >= n_events) return;
    const int s = src[e];
    const int d = dst[e];
    const int te = t[e];
    nxt[2 * e]     = atomicExch(head + s, 2 * e);
    nxt[2 * e + 1] = atomicExch(head + d, 2 * e + 1);
    atomicMax(lu_new + s, te);
    atomicMax(lu_new + d, te);
}

// ---------------- Phase 1b: per-node gather-mean (+ lu_out fused) --------
__global__ __launch_bounds__(256) void tgn_aggregate(
    const int* __restrict__ head, const int* __restrict__ nxt,
    const int* __restrict__ src, const int* __restrict__ dst, const int* __restrict__ t,
    const float* __restrict__ raw_msg, const short* __restrict__ memB,
    const int* __restrict__ last_update,
    const float* __restrict__ time_w, const float* __restrict__ time_b,
    short* __restrict__ ACC, const int* __restrict__ lu, float* __restrict__ out2,
    int n_nodes)
{
    const int n = blockIdx.x * 4 + (threadIdx.x >> 6);
    if (n >= n_nodes) return;
    const int lane = threadIdx.x & 63;
    if (lane == 0) out2[n] = (float)lu[n];
    int k = head[n];
    if (k < 0) return;                       // no events: gru gates via head
    const int j0 = lane * 2;

    const float lus = (float)last_update[n];
    const float2 tw = *reinterpret_cast<const float2*>(time_w + j0);
    const float2 tb = *reinterpret_cast<const float2*>(time_b + j0);

    float am0 = 0.f, am1 = 0.f, ar0 = 0.f, ar1 = 0.f, at0 = 0.f, at1 = 0.f;
    int c = 0;
    while (k >= 0) {
        const int kn = nxt[k];               // issue chase early
        const int e = k >> 1;
        const int other = (k & 1) ? src[e] : dst[e];
        const float te = (float)t[e];
        const float2 rw = *reinterpret_cast<const float2*>(raw_msg + (size_t)e * MEMD + j0);
        const bf16x2 mb = *reinterpret_cast<const bf16x2*>(memB + (size_t)other * MEMD + j0);
        const float dt = te - lus;
        at0 += __cosf(fmaf(dt, tw.x, tb.x));
        at1 += __cosf(fmaf(dt, tw.y, tb.y));
        ar0 += rw.x; ar1 += rw.y;
        am0 += bf2f(mb[0]); am1 += bf2f(mb[1]);
        ++c;
        k = kn;
    }
    const float inv = 1.0f / (float)c;
    short* row = ACC + (size_t)n * ACCD;
    bf16x2 v;
    v[0] = f2bf(am0 * inv); v[1] = f2bf(am1 * inv);
    *reinterpret_cast<bf16x2*>(row + j0) = v;
    v[0] = f2bf(ar0 * inv); v[1] = f2bf(ar1 * inv);
    *reinterpret_cast<bf16x2*>(row + 128 + j0) = v;
    v[0] = f2bf(at0 * inv); v[1] = f2bf(at1 * inv);
    *reinterpret_cast<bf16x2*>(row + 256 + j0) = v;
}

// ---------------- Phase 2: MFMA GEMM + GRU (depth-3 W-prefetch ring) ------
// 512 threads (8 waves), 32 nodes/block. Wave wv owns N-tiles {wv,wv+8,wv+16}.
// 20 unified k-steps: s<4 -> gh (Wh), s>=4 -> gi (Wb, ks=s-4). Ring regs
// rA*/rB*/rC* hold steps s, s+1, s+2; load for s+3 issues after consuming s.
#define WPTR(NN, S) ((S) < 4 ? (Wh + (size_t)((NN) * 4 + (S)) * 64 + lane)      \
                             : (Wb + (size_t)((NN) * 16 + (S) - 4) * 64 + lane))

#define MFMA2(ACCN, BV)                                                          \
    ACCN[0] = __builtin_amdgcn_mfma_f32_16x16x32_bf16(a0, BV, ACCN[0], 0, 0, 0); \
    ACCN[1] = __builtin_amdgcn_mfma_f32_16x16x32_bf16(a1, BV, ACCN[1], 0, 0, 0);

#define STEP(S, B0, B1, B2, ACCARR)                                              \
    {                                                                            \
        const int ks_ = (S) < 4 ? (S) : (S) - 4;                                 \
        const bf16x8 a0 = Xf[(0 * 16 + ks_) * 64 + lane];                        \
        const bf16x8 a1 = Xf[(1 * 16 + ks_) * 64 + lane];                        \
        MFMA2(ACCARR[0], B0)                                                     \
        MFMA2(ACCARR[1], B1)                                                     \
        MFMA2(ACCARR[2], B2)                                                     \
    }                                                                            \
    if ((S) + 3 < 20) {                                                          \
        B0 = *WPTR(n0, (S) + 3);                                                 \
        B1 = *WPTR(n1, (S) + 3);                                                 \
        B2 = *WPTR(n2, (S) + 3);                                                 \
    }

__global__ __launch_bounds__(512, 4) void tgn_gru_mfma(
    const short* __restrict__ memB, const short* __restrict__ ACC,
    const int* __restrict__ head, const bf16x8* __restrict__ Wb,
    const float* __restrict__ b_ih, const float* __restrict__ b_hh,
    float* __restrict__ out, int n_nodes)
{
    __shared__ bf16x8 Xf[2 * 16 * 64];      // 32 KB : X tile (frag-major)
    ushort* Xh = reinterpret_cast<ushort*>(Xf);
    float*  Sout = reinterpret_cast<float*>(Xf);   // reused after mv reads

    const int tid = threadIdx.x;
    const int lane = tid & 63;
    const int wv = tid >> 6;                 // wave id 0..7 (uniform)
    const int node0 = blockIdx.x * 32;

    const bf16x8* __restrict__ Wh = Wb + GI_SLOTS;
    const int n0 = wv, n1 = wv + 8, n2 = wv + 16;

    // ---- stage X tile: pure async copy ----
    #pragma unroll
    for (int i = 0; i < 4; ++i) {
        const int slotbase = i * 512 + (tid & ~63);   // wave-uniform
        const int slot = slotbase + lane;
        const int ks = (slot >> 6) & 15;              // lane-independent
        const int m = slot >> 10;                     // lane-independent (0..1)
        int node = node0 + m * 16 + (lane & 15);
        if (node >= n_nodes) node = n_nodes - 1;
        const int kbase = ks * 32 + (lane >> 4) * 8;
        const short* g = (kbase < 128)
            ? (memB + (size_t)node * MEMD + kbase)
            : (ACC + (size_t)node * ACCD + (kbase - 128));
        load_lds16(g, &Xf[slotbase]);
    }

    // ---- ring prologue: steps 0,1,2 in flight before the drain ----
    bf16x8 rA0 = *WPTR(n0, 0), rA1 = *WPTR(n1, 0), rA2 = *WPTR(n2, 0);
    bf16x8 rB0 = *WPTR(n0, 1), rB1 = *WPTR(n1, 1), rB2 = *WPTR(n2, 1);
    bf16x8 rC0 = *WPTR(n0, 2), rC1 = *WPTR(n1, 2), rC2 = *WPTR(n2, 2);

    asm volatile("s_waitcnt vmcnt(0)" ::: "memory");
    __syncthreads();   // X visible; waves run free from here

    const int col = lane & 15;
    const int rgrp = lane >> 4;

    // hmask gathers issued early (hide under weight stream)
    uint32_t hmask = 0;
    #pragma unroll
    for (int m = 0; m < 2; ++m)
        #pragma unroll
        for (int r = 0; r < 4; ++r) {
            const int node = node0 + m * 16 + rgrp * 4 + r;
            if (node < n_nodes && head[node] >= 0) hmask |= 1u << (m * 4 + r);
        }

    f32x4 acc_i[3][2], acc_h[3][2];
    #pragma unroll
    for (int c = 0; c < 3; ++c)
        #pragma unroll
        for (int m = 0; m < 2; ++m) {
            acc_i[c][m] = (f32x4){0.f, 0.f, 0.f, 0.f};
            acc_h[c][m] = (f32x4){0.f, 0.f, 0.f, 0.f};
        }

    // ---- 20 unified k-steps, ring order A,B,C,A,B,C,... ----
    STEP(0,  rA0, rA1, rA2, acc_h)
    STEP(1,  rB0, rB1, rB2, acc_h)
    STEP(2,  rC0, rC1, rC2, acc_h)
    STEP(3,  rA0, rA1, rA2, acc_h)
    STEP(4,  rB0, rB1, rB2, acc_i)
    STEP(5,  rC0, rC1, rC2, acc_i)
    STEP(6,  rA0, rA1, rA2, acc_i)
    STEP(7,  rB0, rB1, rB2, acc_i)
    STEP(8,  rC0, rC1, rC2, acc_i)
    STEP(9,  rA0, rA1, rA2, acc_i)
    STEP(10, rB0, rB1, rB2, acc_i)
    STEP(11, rC0, rC1, rC2, acc_i)
    STEP(12, rA0, rA1, rA2, acc_i)
    STEP(13, rB0, rB1, rB2, acc_i)
    STEP(14, rC0, rC1, rC2, acc_i)
    STEP(15, rA0, rA1, rA2, acc_i)
    STEP(16, rB0, rB1, rB2, acc_i)
    STEP(17, rC0, rC1, rC2, acc_i)
    STEP(18, rA0, rA1, rA2, acc_i)
    STEP(19, rB0, rB1, rB2, acc_i)

    // ---- GRU epilogue: wave-local triple (j, j+128, j+256) ----
    const int jr = wv * 16 + col;            // 0..127
    const float bir = b_ih[jr], biz = b_ih[jr + 128], bin = b_ih[jr + 256];
    const float bhr = b_hh[jr], bhz = b_hh[jr + 128], bhn = b_hh[jr + 256];
    const int ksj = jr >> 5;
    const int sub = ((jr >> 3) & 3) * 16;
    const int elem = jr & 7;

    float rout[2][4];
    #pragma unroll
    for (int m = 0; m < 2; ++m) {
        #pragma unroll
        for (int r = 0; r < 4; ++r) {
            const bool has = (hmask >> (m * 4 + r)) & 1;
            const float gir = (has ? acc_i[0][m][r] : 0.f) + bir;
            const float giz = (has ? acc_i[1][m][r] : 0.f) + biz;
            const float gin = (has ? acc_i[2][m][r] : 0.f) + bin;
            const float ghr = acc_h[0][m][r] + bhr;
            const float ghz = acc_h[1][m][r] + bhz;
            const float ghn = acc_h[2][m][r] + bhn;
            const float rr = __fdividef(1.0f, 1.0f + __expf(-(gir + ghr)));
            const float zz = __fdividef(1.0f, 1.0f + __expf(-(giz + ghz)));
            const float targ = fmaf(rr, ghn, gin);
            const float e2v = __expf(2.0f * targ);
            const float nn = __fdividef(e2v - 1.0f, e2v + 1.0f);
            const int slot = (m * 16 + ksj) * 64 + sub + (rgrp * 4 + r);
            const float mv = bf2f((short)Xh[slot * 8 + elem]);
            rout[m][r] = (1.0f - zz) * nn + zz * mv;
        }
    }
    __syncthreads();   // all waves done with Xf (mv) -> reuse as Sout

    #pragma unroll
    for (int m = 0; m < 2; ++m)
        #pragma unroll
        for (int r = 0; r < 4; ++r)
            Sout[(m * 16 + rgrp * 4 + r) * MEMD + jr] = rout[m][r];
    __syncthreads();

    // ---- fully-coalesced float4 write-out (32 nodes x 128 f32) ----
    float4* out4 = reinterpret_cast<float4*>(out + (size_t)node0 * MEMD);
    const float4* S4 = reinterpret_cast<const float4*>(Sout);
    if (node0 + 32 <= n_nodes) {
        #pragma unroll
        for (int it = 0; it < 2; ++it)
            out4[it * 512 + tid] = S4[it * 512 + tid];
    } else {
        #pragma unroll
        for (int it = 0; it < 2; ++it) {
            const int idx = it * 512 + tid;
            if (node0 + (idx >> 5) < n_nodes) out4[idx] = S4[idx];
        }
    }
}

extern "C" void kernel_launch(void* const* d_in, const int* in_sizes, int n_in,
                              void* d_out, int out_size, void* d_ws, size_t ws_size,
                              hipStream_t stream)
{
    const float* memory      = (const float*)d_in[0];
    const int*   last_update = (const int*)d_in[1];
    const int*   src         = (const int*)d_in[2];
    const int*   dst         = (const int*)d_in[3];
    const int*   t           = (const int*)d_in[4];
    const float* raw_msg     = (const float*)d_in[5];
    const float* time_w      = (const float*)d_in[6];
    const float* time_b      = (const float*)d_in[7];
    const float* W_ih        = (const float*)d_in[8];
    const float* W_hh        = (const float*)d_in[9];
    const float* b_ih        = (const float*)d_in[10];
    const float* b_hh        = (const float*)d_in[11];

    const int n_nodes  = in_sizes[0] / MEMD;
    const int n_events = in_sizes[2];

    // Workspace: ACC(bf16 means) | head | next | lu | Wb | memB
    short* ACC  = (short*)d_ws;
    int*   head = (int*)(ACC + (size_t)n_nodes * ACCD);
    int*   nxt  = head + n_nodes;
    int*   lu   = nxt + 2 * n_events;
    bf16x8* Wb  = (bf16x8*)(lu + n_nodes);
    short* memB = (short*)(Wb + GI_SLOTS + GH_SLOTS);

    (void)hipMemsetAsync(head, 0xFF, (size_t)n_nodes * sizeof(int), stream); // -1
    (void)hipMemsetAsync(lu, 0, (size_t)n_nodes * sizeof(int), stream);

    tgn_prep_w<<<dim3((GI_SLOTS + GH_SLOTS + 255) / 256), dim3(256), 0, stream>>>(W_ih, W_hh, Wb);

    const int n8 = n_nodes * MEMD / 8;
    tgn_prep_mem<<<dim3((n8 + 255) / 256), dim3(256), 0, stream>>>(memory, memB, n8);

    tgn_fill<<<dim3((n_events + 255) / 256), dim3(256), 0, stream>>>(
        src, dst, t, head, nxt, lu, n_events);

    float* out2 = (float*)d_out + (size_t)n_nodes * MEMD;
    tgn_aggregate<<<dim3((n_nodes + 3) / 4), dim3(256), 0, stream>>>(
        head, nxt, src, dst, t, raw_msg, memB, last_update, time_w, time_b,
        ACC, lu, out2, n_nodes);

    tgn_gru_mfma<<<dim3((n_nodes + 31) / 32), dim3(512), 0, stream>>>(
        memB, ACC, head, Wb, b_ih, b_hh, (float*)d_out, n_nodes);
}

// Round 16
// 334.345 us; speedup vs baseline: 1.1232x; 1.1232x over previous
//
#include <hip/hip_runtime.h>
#include <cstdint>

// TGN memory update — round 16: aggregation FUSED into gru (no ACC buffer,
// no separate aggregate kernel). Wave gathers its 4 nodes' messages into
// frag-layout LDS; memB part staged via global_load_lds; R15 ring GEMM.

#define MEMD 128
#define ACCD 384
#define MSGD 512

typedef __attribute__((ext_vector_type(8))) short bf16x8;
typedef __attribute__((ext_vector_type(2))) short bf16x2;
typedef __attribute__((ext_vector_type(4))) float f32x4;

static __device__ __forceinline__ short f2bf(float f) {
    uint32_t u = __builtin_bit_cast(uint32_t, f);
    u = (u + 0x7FFFu + ((u >> 16) & 1u)) >> 16;
    return (short)u;
}
static __device__ __forceinline__ float bf2f(short s) {
    return __builtin_bit_cast(float, ((uint32_t)(uint16_t)s) << 16);
}
static __device__ __forceinline__ uint32_t pack2bf(float a, float b) {
    return (uint32_t)(uint16_t)f2bf(a) | ((uint32_t)(uint16_t)f2bf(b) << 16);
}
// async 16B global->LDS; LDS dest = wave-uniform base + lane*16, global per-lane
static __device__ __forceinline__ void load_lds16(const void* g, void* l) {
    __builtin_amdgcn_global_load_lds(
        (const __attribute__((address_space(1))) unsigned int*)g,
        (__attribute__((address_space(3))) unsigned int*)l,
        16, 0, 0);
}

// ---------------- Prep A: memory f32 -> bf16 ----------------
__global__ __launch_bounds__(256) void tgn_prep_mem(
    const float* __restrict__ mem, short* __restrict__ memB, int n8)
{
    const int i = blockIdx.x * 256 + threadIdx.x;
    if (i >= n8) return;
    const float4 a = *reinterpret_cast<const float4*>(mem + (size_t)i * 8);
    const float4 b = *reinterpret_cast<const float4*>(mem + (size_t)i * 8 + 4);
    bf16x8 v;
    v[0] = f2bf(a.x); v[1] = f2bf(a.y); v[2] = f2bf(a.z); v[3] = f2bf(a.w);
    v[4] = f2bf(b.x); v[5] = f2bf(b.y); v[6] = f2bf(b.z); v[7] = f2bf(b.w);
    *reinterpret_cast<bf16x8*>(memB + (size_t)i * 8) = v;
}

// ---------------- Prep B: weights f32 -> bf16 frag-major ----------------
#define GI_SLOTS (24 * 16 * 64)
#define GH_SLOTS (24 * 4 * 64)

__global__ __launch_bounds__(256) void tgn_prep_w(
    const float* __restrict__ W_ih, const float* __restrict__ W_hh,
    bf16x8* __restrict__ Wb)
{
    const int s = blockIdx.x * 256 + threadIdx.x;
    if (s >= GI_SLOTS + GH_SLOTS) return;
    const float* src;
    if (s < GI_SLOTS) {
        const int n = s / (16 * 64), rem = s % (16 * 64);
        const int ks = rem / 64, l = rem % 64;
        const int j = n * 16 + (l & 15), k = ks * 32 + (l >> 4) * 8;
        src = W_ih + (size_t)j * MSGD + k;
    } else {
        const int s2 = s - GI_SLOTS;
        const int n = s2 / (4 * 64), rem = s2 % (4 * 64);
        const int ks = rem / 64, l = rem % 64;
        const int j = n * 16 + (l & 15), k = ks * 32 + (l >> 4) * 8;
        src = W_hh + (size_t)j * MEMD + k;
    }
    bf16x8 v;
    #pragma unroll
    for (int e = 0; e < 8; ++e) v[e] = f2bf(src[e]);
    Wb[s] = v;
}

// ---------------- Phase 1: build per-node linked lists ----------------
__global__ __launch_bounds__(256) void tgn_fill(
    const int* __restrict__ src, const int* __restrict__ dst, const int* __restrict__ t,
    int* __restrict__ head, int* __restrict__ nxt, int* __restrict__ lu_new,
    int n_events)
{
    const int e = blockIdx.x * 256 + threadIdx.x;
    if (e >= n_events) return;
    const int s = src[e];
    const int d = dst[e];
    const int te = t[e];
    nxt[2 * e]     = atomicExch(head + s, 2 * e);
    nxt[2 * e + 1] = atomicExch(head + d, 2 * e + 1);
    atomicMax(lu_new + s, te);
    atomicMax(lu_new + d, te);
}

// ---------------- Phase 2: fused gather + MFMA GEMM + GRU ----------------
// 512 threads (8 waves), 32 nodes/block. Wave wv: gathers nodes wv*4..+3,
// owns N-tiles {wv, wv+8, wv+16}. Depth-3 weight ring, no loop barriers.
#define WPTR(NN, S) ((S) < 4 ? (Wh + (size_t)((NN) * 4 + (S)) * 64 + lane)      \
                             : (Wb + (size_t)((NN) * 16 + (S) - 4) * 64 + lane))

#define MFMA2(ACCN, BV)                                                          \
    ACCN[0] = __builtin_amdgcn_mfma_f32_16x16x32_bf16(a0, BV, ACCN[0], 0, 0, 0); \
    ACCN[1] = __builtin_amdgcn_mfma_f32_16x16x32_bf16(a1, BV, ACCN[1], 0, 0, 0);

#define STEP(S, B0, B1, B2, ACCARR)                                              \
    {                                                                            \
        const int ks_ = (S) < 4 ? (S) : (S) - 4;                                 \
        const bf16x8 a0 = Xf[(0 * 16 + ks_) * 64 + lane];                        \
        const bf16x8 a1 = Xf[(1 * 16 + ks_) * 64 + lane];                        \
        MFMA2(ACCARR[0], B0)                                                     \
        MFMA2(ACCARR[1], B1)                                                     \
        MFMA2(ACCARR[2], B2)                                                     \
    }                                                                            \
    if ((S) + 3 < 20) {                                                          \
        B0 = *WPTR(n0, (S) + 3);                                                 \
        B1 = *WPTR(n1, (S) + 3);                                                 \
        B2 = *WPTR(n2, (S) + 3);                                                 \
    }

__global__ __launch_bounds__(512, 4) void tgn_gru_fused(
    const short* __restrict__ memB, const int* __restrict__ head,
    const int* __restrict__ nxt,
    const int* __restrict__ src, const int* __restrict__ dst,
    const int* __restrict__ t, const float* __restrict__ raw_msg,
    const int* __restrict__ last_update,
    const float* __restrict__ time_w, const float* __restrict__ time_b,
    const bf16x8* __restrict__ Wb,
    const float* __restrict__ b_ih, const float* __restrict__ b_hh,
    const int* __restrict__ lu, float* __restrict__ out,
    float* __restrict__ out2, int n_nodes)
{
    __shared__ bf16x8 Xf[2 * 16 * 64];      // 32 KB : X tile (frag-major)
    ushort* Xh = reinterpret_cast<ushort*>(Xf);
    uint32_t* X32 = reinterpret_cast<uint32_t*>(Xf);
    float*  Sout = reinterpret_cast<float*>(Xf);   // reused after mv reads

    const int tid = threadIdx.x;
    const int lane = tid & 63;
    const int wv = tid >> 6;                 // wave id 0..7 (uniform)
    const int node0 = blockIdx.x * 32;

    const bf16x8* __restrict__ Wh = Wb + GI_SLOTS;
    const int n0 = wv, n1 = wv + 8, n2 = wv + 16;

    // ---- stage memB quarter of X (ks 0..3): one async pass ----
    // wave wv covers (m = wv>>2, ks = wv&3): slotbase wave-uniform.
    {
        const int m = wv >> 2, ks = wv & 3;
        const int slotbase = (m * 16 + ks) * 64;
        int node = node0 + m * 16 + (lane & 15);
        if (node >= n_nodes) node = n_nodes - 1;
        const int kbase = ks * 32 + (lane >> 4) * 8;
        load_lds16(memB + (size_t)node * MEMD + kbase, &Xf[slotbase]);
    }

    // ---- ring prologue: weight steps 0,1,2 in flight ----
    bf16x8 rA0 = *WPTR(n0, 0), rA1 = *WPTR(n1, 0), rA2 = *WPTR(n2, 0);
    bf16x8 rB0 = *WPTR(n0, 1), rB1 = *WPTR(n1, 1), rB2 = *WPTR(n2, 1);
    bf16x8 rC0 = *WPTR(n0, 2), rC1 = *WPTR(n1, 2), rC2 = *WPTR(n2, 2);

    // ---- gather: wave wv aggregates nodes node0+wv*4 .. +3 ----
    // lane owns dims {2*lane, 2*lane+1} of each 128-part; mean in f32 regs;
    // written into frag-layout LDS as one u32 per part.
    {
        const int j0 = lane * 2;
        const float2 tw = *reinterpret_cast<const float2*>(time_w + j0);
        const float2 tb = *reinterpret_cast<const float2*>(time_b + j0);
        #pragma unroll
        for (int q = 0; q < 4; ++q) {
            const int n = node0 + wv * 4 + q;
            if (n >= n_nodes) break;
            int k = head[n];
            if (k < 0) continue;             // empty: Xf garbage, gated by hmask
            const float lus = (float)last_update[n];
            float am0 = 0.f, am1 = 0.f, ar0 = 0.f, ar1 = 0.f, at0 = 0.f, at1 = 0.f;
            int c = 0;
            while (k >= 0) {
                const int kn = nxt[k];
                const int e = k >> 1;
                const int other = (k & 1) ? src[e] : dst[e];
                const float te = (float)t[e];
                const float2 rw = *reinterpret_cast<const float2*>(raw_msg + (size_t)e * MEMD + j0);
                const bf16x2 mb = *reinterpret_cast<const bf16x2*>(memB + (size_t)other * MEMD + j0);
                const float dt = te - lus;
                at0 += __cosf(fmaf(dt, tw.x, tb.x));
                at1 += __cosf(fmaf(dt, tw.y, tb.y));
                ar0 += rw.x; ar1 += rw.y;
                am0 += bf2f(mb[0]); am1 += bf2f(mb[1]);
                ++c;
                k = kn;
            }
            const float inv = 1.0f / (float)c;
            const int nn_ = wv * 4 + q;
            const int mn = nn_ >> 4, nif = nn_ & 15;
            #pragma unroll
            for (int p = 0; p < 3; ++p) {
                const int cc = 128 + p * 128 + j0;       // X column of dim pair
                const int ks = cc >> 5;
                const int hi = (cc >> 3) & 3;
                const int u32idx = ((mn * 16 + ks) * 64 + hi * 16 + nif) * 4 + (lane & 3);
                const float v0 = (p == 0 ? am0 : p == 1 ? ar0 : at0) * inv;
                const float v1 = (p == 0 ? am1 : p == 1 ? ar1 : at1) * inv;
                X32[u32idx] = pack2bf(v0, v1);
            }
        }
    }

    asm volatile("s_waitcnt vmcnt(0)" ::: "memory");
    __syncthreads();   // X fully assembled; waves run free from here

    const int col = lane & 15;
    const int rgrp = lane >> 4;

    uint32_t hmask = 0;
    #pragma unroll
    for (int m = 0; m < 2; ++m)
        #pragma unroll
        for (int r = 0; r < 4; ++r) {
            const int node = node0 + m * 16 + rgrp * 4 + r;
            if (node < n_nodes && head[node] >= 0) hmask |= 1u << (m * 4 + r);
        }

    f32x4 acc_i[3][2], acc_h[3][2];
    #pragma unroll
    for (int c = 0; c < 3; ++c)
        #pragma unroll
        for (int m = 0; m < 2; ++m) {
            acc_i[c][m] = (f32x4){0.f, 0.f, 0.f, 0.f};
            acc_h[c][m] = (f32x4){0.f, 0.f, 0.f, 0.f};
        }

    // ---- 20 unified k-steps (gh 0..3 on Wh, gi 4..19 on Wb), ring ----
    STEP(0,  rA0, rA1, rA2, acc_h)
    STEP(1,  rB0, rB1, rB2, acc_h)
    STEP(2,  rC0, rC1, rC2, acc_h)
    STEP(3,  rA0, rA1, rA2, acc_h)
    STEP(4,  rB0, rB1, rB2, acc_i)
    STEP(5,  rC0, rC1, rC2, acc_i)
    STEP(6,  rA0, rA1, rA2, acc_i)
    STEP(7,  rB0, rB1, rB2, acc_i)
    STEP(8,  rC0, rC1, rC2, acc_i)
    STEP(9,  rA0, rA1, rA2, acc_i)
    STEP(10, rB0, rB1, rB2, acc_i)
    STEP(11, rC0, rC1, rC2, acc_i)
    STEP(12, rA0, rA1, rA2, acc_i)
    STEP(13, rB0, rB1, rB2, acc_i)
    STEP(14, rC0, rC1, rC2, acc_i)
    STEP(15, rA0, rA1, rA2, acc_i)
    STEP(16, rB0, rB1, rB2, acc_i)
    STEP(17, rC0, rC1, rC2, acc_i)
    STEP(18, rA0, rA1, rA2, acc_i)
    STEP(19, rB0, rB1, rB2, acc_i)

    // ---- GRU epilogue: wave-local triple (j, j+128, j+256) ----
    const int jr = wv * 16 + col;            // 0..127
    const float bir = b_ih[jr], biz = b_ih[jr + 128], bin = b_ih[jr + 256];
    const float bhr = b_hh[jr], bhz = b_hh[jr + 128], bhn = b_hh[jr + 256];
    const int ksj = jr >> 5;
    const int sub = ((jr >> 3) & 3) * 16;
    const int elem = jr & 7;

    float rout[2][4];
    #pragma unroll
    for (int m = 0; m < 2; ++m) {
        #pragma unroll
        for (int r = 0; r < 4; ++r) {
            const bool has = (hmask >> (m * 4 + r)) & 1;
            const float gir = (has ? acc_i[0][m][r] : 0.f) + bir;
            const float giz = (has ? acc_i[1][m][r] : 0.f) + biz;
            const float gin = (has ? acc_i[2][m][r] : 0.f) + bin;
            const float ghr = acc_h[0][m][r] + bhr;
            const float ghz = acc_h[1][m][r] + bhz;
            const float ghn = acc_h[2][m][r] + bhn;
            const float rr = __fdividef(1.0f, 1.0f + __expf(-(gir + ghr)));
            const float zz = __fdividef(1.0f, 1.0f + __expf(-(giz + ghz)));
            const float targ = fmaf(rr, ghn, gin);
            const float e2v = __expf(2.0f * targ);
            const float nn = __fdividef(e2v - 1.0f, e2v + 1.0f);
            const int slot = (m * 16 + ksj) * 64 + sub + (rgrp * 4 + r);
            const float mv = bf2f((short)Xh[slot * 8 + elem]);
            rout[m][r] = (1.0f - zz) * nn + zz * mv;
        }
    }
    // fused last_update output (32 values per block)
    if (tid < 32 && node0 + tid < n_nodes) out2[node0 + tid] = (float)lu[node0 + tid];
    __syncthreads();   // all waves done with Xf (mv) -> reuse as Sout

    #pragma unroll
    for (int m = 0; m < 2; ++m)
        #pragma unroll
        for (int r = 0; r < 4; ++r)
            Sout[(m * 16 + rgrp * 4 + r) * MEMD + jr] = rout[m][r];
    __syncthreads();

    // ---- fully-coalesced float4 write-out (32 nodes x 128 f32) ----
    float4* out4 = reinterpret_cast<float4*>(out + (size_t)node0 * MEMD);
    const float4* S4 = reinterpret_cast<const float4*>(Sout);
    if (node0 + 32 <= n_nodes) {
        #pragma unroll
        for (int it = 0; it < 2; ++it)
            out4[it * 512 + tid] = S4[it * 512 + tid];
    } else {
        #pragma unroll
        for (int it = 0; it < 2; ++it) {
            const int idx = it * 512 + tid;
            if (node0 + (idx >> 5) < n_nodes) out4[idx] = S4[idx];
        }
    }
}

extern "C" void kernel_launch(void* const* d_in, const int* in_sizes, int n_in,
                              void* d_out, int out_size, void* d_ws, size_t ws_size,
                              hipStream_t stream)
{
    const float* memory      = (const float*)d_in[0];
    const int*   last_update = (const int*)d_in[1];
    const int*   src         = (const int*)d_in[2];
    const int*   dst         = (const int*)d_in[3];
    const int*   t           = (const int*)d_in[4];
    const float* raw_msg     = (const float*)d_in[5];
    const float* time_w      = (const float*)d_in[6];
    const float* time_b      = (const float*)d_in[7];
    const float* W_ih        = (const float*)d_in[8];
    const float* W_hh        = (const float*)d_in[9];
    const float* b_ih        = (const float*)d_in[10];
    const float* b_hh        = (const float*)d_in[11];

    const int n_nodes  = in_sizes[0] / MEMD;
    const int n_events = in_sizes[2];

    // Workspace: head | next | lu | Wb | memB   (ACC eliminated)
    int*   head = (int*)d_ws;
    int*   nxt  = head + n_nodes;
    int*   lu   = nxt + 2 * n_events;
    bf16x8* Wb  = (bf16x8*)(lu + n_nodes);
    short* memB = (short*)(Wb + GI_SLOTS + GH_SLOTS);

    (void)hipMemsetAsync(head, 0xFF, (size_t)n_nodes * sizeof(int), stream); // -1
    (void)hipMemsetAsync(lu, 0, (size_t)n_nodes * sizeof(int), stream);

    tgn_prep_w<<<dim3((GI_SLOTS + GH_SLOTS + 255) / 256), dim3(256), 0, stream>>>(W_ih, W_hh, Wb);

    const int n8 = n_nodes * MEMD / 8;
    tgn_prep_mem<<<dim3((n8 + 255) / 256), dim3(256), 0, stream>>>(memory, memB, n8);

    tgn_fill<<<dim3((n_events + 255) / 256), dim3(256), 0, stream>>>(
        src, dst, t, head, nxt, lu, n_events);

    float* out2 = (float*)d_out + (size_t)n_nodes * MEMD;
    tgn_gru_fused<<<dim3((n_nodes + 31) / 32), dim3(512), 0, stream>>>(
        memB, head, nxt, src, dst, t, raw_msg, last_update, time_w, time_b,
        Wb, b_ih, b_hh, lu, (float*)d_out, out2, n_nodes);
}